// Round 1
// baseline (4374.245 us; speedup 1.0000x reference)
//
#include <hip/hip_runtime.h>
#include <cstdint>
#include <cstddef>

// Problem constants
#define BB 2
#define LL 2048
#define EE 1024
#define HH 16
#define DD 64
#define NROW 4096            // B*L
#define ATTN_OUT_ELEMS 4194304ULL        // B*L*E
#define ATTN_W_ELEMS   134217728ULL      // B*H*L*L

// ---------------------------------------------------------------------------
// Cox-de Boor, k=3, grid_size=4, uniform knots g[t] = -2.5 + 0.5*t, t=0..10.
// Produces the 7 cubic B-spline bases exactly as the reference recursion.
// ---------------------------------------------------------------------------
__device__ __forceinline__ void bspline7(float x, float* __restrict__ b) {
    float b0[10];
#pragma unroll
    for (int t = 0; t < 10; ++t) {
        float g0 = -2.5f + 0.5f * (float)t;
        float g1 = g0 + 0.5f;
        b0[t] = (x >= g0 && x < g1) ? 1.0f : 0.0f;
    }
    float b1[9];
#pragma unroll
    for (int t = 0; t < 9; ++t) {
        float g0 = -2.5f + 0.5f * (float)t;
        float l = (x - g0) * 2.0f;            // denom p*h = 0.5
        float r = ((g0 + 1.0f) - x) * 2.0f;   // g[t+2]-x
        b1[t] = l * b0[t] + r * b0[t + 1];
    }
    float b2[8];
#pragma unroll
    for (int t = 0; t < 8; ++t) {
        float g0 = -2.5f + 0.5f * (float)t;
        float l = (x - g0);                   // denom 1.0
        float r = ((g0 + 1.5f) - x);          // g[t+3]-x
        b2[t] = l * b1[t] + r * b1[t + 1];
    }
#pragma unroll
    for (int t = 0; t < 7; ++t) {
        float g0 = -2.5f + 0.5f * (float)t;
        float l = (x - g0) * (1.0f / 1.5f);   // denom 1.5
        float r = ((g0 + 2.0f) - x) * (1.0f / 1.5f);  // g[t+4]-x
        b[t] = l * b2[t] + r * b2[t + 1];
    }
}

// ---------------------------------------------------------------------------
// KAN linear: y[n,o] = sum_i x[n,i]*bw[o,i] + sum_{i,j} sb[n,i,j]*sw[o,i,j]*sc[o,i]
// Treated as GEMM with augmented K = 1024*8 (per feature: x + 7 bases).
// Block: 64x64 output tile, 256 threads, 4x4 acc/thread, BK = 16 feats = 128.
// Bases are computed on the fly during A staging (no augmented-X buffer).
// ---------------------------------------------------------------------------
__global__ __launch_bounds__(256) void kan_gemm(
    const float* __restrict__ x,   // [4096,1024]
    const float* __restrict__ bw,  // [1024,1024]
    const float* __restrict__ sw,  // [1024,1024,7]
    const float* __restrict__ sc,  // [1024,1024]
    float* __restrict__ y)         // [4096,1024]
{
    __shared__ float As[128][64];  // [kk][n]
    __shared__ float Bs[128][64];  // [kk][o]

    const int n0 = blockIdx.y * 64;
    const int o0 = blockIdx.x * 64;
    const int tid = threadIdx.x;
    const int tx = tid & 15;       // col group
    const int ty = tid >> 4;       // row group

    float acc[4][4];
#pragma unroll
    for (int i = 0; i < 4; ++i)
#pragma unroll
        for (int j = 0; j < 4; ++j) acc[i][j] = 0.0f;

    const int an = tid >> 2;            // 0..63 (row for A staging / col for B)
    const int afi = (tid & 3) * 4;      // feature group 0,4,8,12

    for (int i0 = 0; i0 < EE; i0 += 16) {
        // ---- stage A (x + bases) ----
        {
            const float4 xv = *(const float4*)&x[(size_t)(n0 + an) * EE + i0 + afi];
            float xs[4] = {xv.x, xv.y, xv.z, xv.w};
#pragma unroll
            for (int q = 0; q < 4; ++q) {
                float bb[7];
                bspline7(xs[q], bb);
                int kk = (afi + q) * 8;
                As[kk][an] = xs[q];
#pragma unroll
                for (int j = 0; j < 7; ++j) As[kk + 1 + j][an] = bb[j];
            }
        }
        // ---- stage B (base_w + spline_w*scaler) ----
        {
            const float4 bwv = *(const float4*)&bw[(size_t)(o0 + an) * EE + i0 + afi];
            const float4 scv = *(const float4*)&sc[(size_t)(o0 + an) * EE + i0 + afi];
            float bws[4] = {bwv.x, bwv.y, bwv.z, bwv.w};
            float scs[4] = {scv.x, scv.y, scv.z, scv.w};
#pragma unroll
            for (int q = 0; q < 4; ++q) {
                int kk = (afi + q) * 8;
                Bs[kk][an] = bws[q];
                const float* swp = &sw[((size_t)(o0 + an) * EE + (size_t)(i0 + afi + q)) * 7];
#pragma unroll
                for (int j = 0; j < 7; ++j) Bs[kk + 1 + j][an] = swp[j] * scs[q];
            }
        }
        __syncthreads();
#pragma unroll 8
        for (int kk = 0; kk < 128; ++kk) {
            float a[4], b[4];
            *(float4*)a = *(const float4*)&As[kk][ty * 4];
            *(float4*)b = *(const float4*)&Bs[kk][tx * 4];
#pragma unroll
            for (int i = 0; i < 4; ++i)
#pragma unroll
                for (int j = 0; j < 4; ++j) acc[i][j] += a[i] * b[j];
        }
        __syncthreads();
    }

#pragma unroll
    for (int i = 0; i < 4; ++i) {
        float4 v = make_float4(acc[i][0], acc[i][1], acc[i][2], acc[i][3]);
        *(float4*)&y[(size_t)(n0 + ty * 4 + i) * EE + o0 + tx * 4] = v;
    }
}

// ---------------------------------------------------------------------------
// scores = Q K^T / 8 per (b,h).  M=N=2048, K=64 (one shot).
// grid: (ktile 32, qtile 32, bh 32); 64x64 tile, 256 thr, 4x4/thread.
// Tiles staged transposed (Qs[d][q], Ks[d][k], row stride 68) for float4 reads.
// ---------------------------------------------------------------------------
__global__ __launch_bounds__(256) void scores_gemm(
    const float* __restrict__ Qb,  // [4096,1024] (head-interleaved)
    const float* __restrict__ Kb,
    float* __restrict__ S)         // [32, 2048, 2048]
{
    __shared__ float Qs[64][68];
    __shared__ float Ks[64][68];

    const int bh = blockIdx.z;          // b*16+h
    const int b = bh >> 4, h = bh & 15;
    const int q0 = blockIdx.y * 64;
    const int k0 = blockIdx.x * 64;
    const int tid = threadIdx.x;
    const int tx = tid & 15, ty = tid >> 4;

    // stage transposed
    {
        const int r = tid >> 2;           // 0..63
        const int c16 = (tid & 3) * 16;   // 0,16,32,48
        const size_t qbase = ((size_t)b * LL + q0 + r) * EE + h * DD + c16;
        const size_t kbase = ((size_t)b * LL + k0 + r) * EE + h * DD + c16;
#pragma unroll
        for (int m4 = 0; m4 < 4; ++m4) {
            float4 qv = *(const float4*)&Qb[qbase + m4 * 4];
            float4 kv = *(const float4*)&Kb[kbase + m4 * 4];
            Qs[c16 + m4 * 4 + 0][r] = qv.x; Qs[c16 + m4 * 4 + 1][r] = qv.y;
            Qs[c16 + m4 * 4 + 2][r] = qv.z; Qs[c16 + m4 * 4 + 3][r] = qv.w;
            Ks[c16 + m4 * 4 + 0][r] = kv.x; Ks[c16 + m4 * 4 + 1][r] = kv.y;
            Ks[c16 + m4 * 4 + 2][r] = kv.z; Ks[c16 + m4 * 4 + 3][r] = kv.w;
        }
    }
    __syncthreads();

    float acc[4][4];
#pragma unroll
    for (int i = 0; i < 4; ++i)
#pragma unroll
        for (int j = 0; j < 4; ++j) acc[i][j] = 0.0f;

#pragma unroll 8
    for (int kk = 0; kk < 64; ++kk) {
        float a[4], bb[4];
        *(float4*)a = *(const float4*)&Qs[kk][ty * 4];
        *(float4*)bb = *(const float4*)&Ks[kk][tx * 4];
#pragma unroll
        for (int i = 0; i < 4; ++i)
#pragma unroll
            for (int j = 0; j < 4; ++j) acc[i][j] += a[i] * bb[j];
    }

    const size_t sbase = ((size_t)bh * LL + q0 + ty * 4) * LL + k0 + tx * 4;
#pragma unroll
    for (int i = 0; i < 4; ++i) {
        float4 v = make_float4(acc[i][0] * 0.125f, acc[i][1] * 0.125f,
                               acc[i][2] * 0.125f, acc[i][3] * 0.125f);
        *(float4*)&S[sbase + (size_t)i * LL] = v;
    }
}

// ---------------------------------------------------------------------------
// In-place row softmax over 2048 cols. One 256-thread block per row.
// ---------------------------------------------------------------------------
__global__ __launch_bounds__(256) void softmax_rows(float* __restrict__ S)
{
    __shared__ float red[8];
    const size_t row = blockIdx.x;
    float* p = S + row * (size_t)LL;
    const int t = threadIdx.x;
    const int wave = t >> 6, lane = t & 63;

    float4 v0 = ((const float4*)p)[t];
    float4 v1 = ((const float4*)p)[t + 256];

    float m = fmaxf(fmaxf(fmaxf(v0.x, v0.y), fmaxf(v0.z, v0.w)),
                    fmaxf(fmaxf(v1.x, v1.y), fmaxf(v1.z, v1.w)));
#pragma unroll
    for (int off = 32; off > 0; off >>= 1) m = fmaxf(m, __shfl_down(m, off, 64));
    if (lane == 0) red[wave] = m;
    __syncthreads();
    m = fmaxf(fmaxf(red[0], red[1]), fmaxf(red[2], red[3]));

    v0.x = expf(v0.x - m); v0.y = expf(v0.y - m);
    v0.z = expf(v0.z - m); v0.w = expf(v0.w - m);
    v1.x = expf(v1.x - m); v1.y = expf(v1.y - m);
    v1.z = expf(v1.z - m); v1.w = expf(v1.w - m);

    float s = v0.x + v0.y + v0.z + v0.w + v1.x + v1.y + v1.z + v1.w;
#pragma unroll
    for (int off = 32; off > 0; off >>= 1) s += __shfl_down(s, off, 64);
    __syncthreads();
    if (lane == 0) red[wave + 4] = s;
    __syncthreads();
    s = red[4] + red[5] + red[6] + red[7];
    float r = 1.0f / s;

    v0.x *= r; v0.y *= r; v0.z *= r; v0.w *= r;
    v1.x *= r; v1.y *= r; v1.z *= r; v1.w *= r;
    ((float4*)p)[t] = v0;
    ((float4*)p)[t + 256] = v1;
}

// ---------------------------------------------------------------------------
// out = A @ V per (b,h). M=2048, N=64, K=2048 (BK=64).
// grid: (qtile 32, bh 32). A staged transposed (As[k][q]), V natural (Vs[k][d]).
// Writes head-interleaved into attn_output.
// ---------------------------------------------------------------------------
__global__ __launch_bounds__(256) void av_gemm(
    const float* __restrict__ A,   // [32,2048,2048] softmaxed
    const float* __restrict__ Vb,  // [4096,1024]
    float* __restrict__ out)       // [2,2048,1024]
{
    __shared__ float As[64][68];   // [k][q]
    __shared__ float Vs[64][68];   // [k][d]

    const int bh = blockIdx.y;
    const int b = bh >> 4, h = bh & 15;
    const int q0 = blockIdx.x * 64;
    const int tid = threadIdx.x;
    const int tx = tid & 15, ty = tid >> 4;
    const int r = tid >> 2;
    const int c16 = (tid & 3) * 16;

    float acc[4][4];
#pragma unroll
    for (int i = 0; i < 4; ++i)
#pragma unroll
        for (int j = 0; j < 4; ++j) acc[i][j] = 0.0f;

    for (int k0 = 0; k0 < LL; k0 += 64) {
        // A tile [q][k] -> transposed LDS
        {
            const size_t abase = ((size_t)bh * LL + q0 + r) * LL + k0 + c16;
#pragma unroll
            for (int m4 = 0; m4 < 4; ++m4) {
                float4 av = *(const float4*)&A[abase + m4 * 4];
                As[c16 + m4 * 4 + 0][r] = av.x; As[c16 + m4 * 4 + 1][r] = av.y;
                As[c16 + m4 * 4 + 2][r] = av.z; As[c16 + m4 * 4 + 3][r] = av.w;
            }
        }
        // V tile [k][d] natural
        {
            const size_t vbase = ((size_t)b * LL + k0 + r) * EE + h * DD + c16;
#pragma unroll
            for (int m4 = 0; m4 < 4; ++m4) {
                float4 vv = *(const float4*)&Vb[vbase + m4 * 4];
                *(float4*)&Vs[r][c16 + m4 * 4] = vv;
            }
        }
        __syncthreads();
#pragma unroll 8
        for (int kk = 0; kk < 64; ++kk) {
            float a[4], bb[4];
            *(float4*)a = *(const float4*)&As[kk][ty * 4];
            *(float4*)bb = *(const float4*)&Vs[kk][tx * 4];
#pragma unroll
            for (int i = 0; i < 4; ++i)
#pragma unroll
                for (int j = 0; j < 4; ++j) acc[i][j] += a[i] * bb[j];
        }
        __syncthreads();
    }

#pragma unroll
    for (int i = 0; i < 4; ++i) {
        float4 v = make_float4(acc[i][0], acc[i][1], acc[i][2], acc[i][3]);
        *(float4*)&out[((size_t)b * LL + q0 + ty * 4 + i) * EE + h * DD + tx * 4] = v;
    }
}

// ---------------------------------------------------------------------------
extern "C" void kernel_launch(void* const* d_in, const int* in_sizes, int n_in,
                              void* d_out, int out_size, void* d_ws, size_t ws_size,
                              hipStream_t stream) {
    const float* query    = (const float*)d_in[0];
    const float* key      = (const float*)d_in[1];
    const float* value    = (const float*)d_in[2];
    const float* q_base   = (const float*)d_in[3];
    const float* q_spline = (const float*)d_in[4];
    const float* q_scaler = (const float*)d_in[5];
    const float* k_base   = (const float*)d_in[6];
    const float* k_spline = (const float*)d_in[7];
    const float* k_scaler = (const float*)d_in[8];
    const float* v_base   = (const float*)d_in[9];
    const float* v_spline = (const float*)d_in[10];
    const float* v_scaler = (const float*)d_in[11];

    float* attn_out = (float*)d_out;                      // [2,2048,1024]
    float* attn_w   = (float*)d_out + ATTN_OUT_ELEMS;     // [2,16,2048,2048]

    float* Qbuf = (float*)d_ws;                           // [4096,1024]
    float* Kbuf = Qbuf + (size_t)NROW * EE;
    float* Vbuf = Kbuf + (size_t)NROW * EE;

    dim3 g1(EE / 64, NROW / 64);   // (16, 64)
    kan_gemm<<<g1, 256, 0, stream>>>(query, q_base, q_spline, q_scaler, Qbuf);
    kan_gemm<<<g1, 256, 0, stream>>>(key,   k_base, k_spline, k_scaler, Kbuf);
    kan_gemm<<<g1, 256, 0, stream>>>(value, v_base, v_spline, v_scaler, Vbuf);

    dim3 g2(LL / 64, LL / 64, BB * HH);  // (32, 32, 32)
    scores_gemm<<<g2, 256, 0, stream>>>(Qbuf, Kbuf, attn_w);

    softmax_rows<<<(uint32_t)(BB * HH * LL), 256, 0, stream>>>(attn_w);

    dim3 g4(LL / 64, BB * HH);  // (32, 32)
    av_gemm<<<g4, 256, 0, stream>>>(attn_w, Vbuf, attn_out);
}